// Round 9
// baseline (536.586 us; speedup 1.0000x reference)
//
#include <hip/hip_runtime.h>
#include <hip/hip_bf16.h>
#include <math.h>

#define NN 50000
#define EE 250000
#define SCAN_T 1024
#define CHUNK 49  // 1024*49 = 50176 >= NN

typedef __attribute__((ext_vector_type(8))) short bf16x8;
typedef __attribute__((ext_vector_type(4))) float f32x4;

__device__ __forceinline__ float wsum64(float v) {
  v += __shfl_xor(v, 1, 64);
  v += __shfl_xor(v, 2, 64);
  v += __shfl_xor(v, 4, 64);
  v += __shfl_xor(v, 8, 64);
  v += __shfl_xor(v, 16, 64);
  v += __shfl_xor(v, 32, 64);
  return v;
}

__device__ __forceinline__ float gelu_exact(float a) {
  return 0.5f * a * (1.0f + erff(a * 0.70710678118654752f));
}

// convert 4 packed bf16 (8B as uint2) to 4 floats
__device__ __forceinline__ void bf4_to_f(const uint2 u, float* f) {
  f[0] = __uint_as_float(u.x << 16);
  f[1] = __uint_as_float(u.x & 0xffff0000u);
  f[2] = __uint_as_float(u.y << 16);
  f[3] = __uint_as_float(u.y & 0xffff0000u);
}

// ---------------- weight converter: Wq/Wk/Wv/Wskip -> bf16 MFMA-B-fragment layout
__global__ __launch_bounds__(256) void convert_wb_kernel(
    const float* __restrict__ Wq, const float* __restrict__ Wk,
    const float* __restrict__ Wv, const float* __restrict__ Ws,
    __hip_bfloat16* __restrict__ Wb) {
  const int tid = blockIdx.x * 256 + threadIdx.x;  // 0 .. 2*53248-1
  const int layer = tid / 53248;
  const int rem = tid % 53248;
  const int i = rem & 7;
  const int l = (rem >> 3) & 63;
  const int fct = rem >> 9;        // ct*2 + f
  const int f = fct & 1;
  const int ct = fct >> 1;
  const int col = ct * 16 + (l & 15);
  const int kk = f * 32 + (l >> 4) * 8 + i;
  float val;
  if (col < 256)      val = Wq[(size_t)layer * 16384 + kk * 256 + col];
  else if (col < 512) val = Wk[(size_t)layer * 16384 + kk * 256 + (col - 256)];
  else if (col < 768) val = Wv[(size_t)layer * 16384 + kk * 256 + (col - 512)];
  else                val = Ws[(size_t)layer * 4096 + kk * 64 + (col - 768)];
  Wb[tid] = __float2bfloat16(val);
}

// ---------------- CSR build ----------------
__global__ __launch_bounds__(256) void hist_kernel(const int* __restrict__ ei,
                                                   int* __restrict__ cnt) {
  const int e = blockIdx.x * 256 + threadIdx.x;
  if (e < EE) atomicAdd(&cnt[ei[EE + e]], 1);
}

__global__ __launch_bounds__(SCAN_T) void scan_kernel(
    const int* __restrict__ cnt, int* __restrict__ offs,
    int* __restrict__ cursor) {
  __shared__ int part[SCAN_T];
  const int t = threadIdx.x;
  const int base = t * CHUNK;
  int s = 0;
  for (int i = 0; i < CHUNK; i++) {
    int idx = base + i;
    s += (idx < NN) ? cnt[idx] : 0;
  }
  part[t] = s;
  __syncthreads();
  // Hillis-Steele inclusive scan
  for (int off = 1; off < SCAN_T; off <<= 1) {
    int val = (t >= off) ? part[t - off] : 0;
    __syncthreads();
    part[t] += val;
    __syncthreads();
  }
  int run = (t == 0) ? 0 : part[t - 1];
  for (int i = 0; i < CHUNK; i++) {
    int idx = base + i;
    if (idx < NN) {
      offs[idx] = run;
      cursor[idx] = run;
      run += cnt[idx];
    }
  }
  if (t == 0) offs[NN] = EE;
}

__global__ __launch_bounds__(256) void scatter_kernel(
    const int* __restrict__ ei, const float* __restrict__ ea,
    int* __restrict__ cursor, int* __restrict__ src_sorted,
    float4* __restrict__ ea_sorted) {
  const int e = blockIdx.x * 256 + threadIdx.x;
  if (e >= EE) return;
  const int dst = ei[EE + e];
  const int pos = atomicAdd(&cursor[dst], 1);
  src_sorted[pos] = ei[e];
  ea_sorted[pos] = reinterpret_cast<const float4*>(ea)[e];
}

// ---------------- encoder ----------------
__global__ __launch_bounds__(256) void enc_kernel(
    const float* __restrict__ x, const float* __restrict__ w1,
    const float* __restrict__ b1, const float* __restrict__ lg,
    const float* __restrict__ lb, const float* __restrict__ w2,
    const float* __restrict__ b2, float* __restrict__ h,
    __hip_bfloat16* __restrict__ hb) {
  const int t = blockIdx.x * 256 + threadIdx.x;
  const int node = t >> 6;
  const int lane = t & 63;
  const int wib = (threadIdx.x >> 6);
  __shared__ float gS[4][64];
  if (node < NN) {
    float a = b1[lane];
    #pragma unroll
    for (int d = 0; d < 6; d++) a += x[(size_t)node * 6 + d] * w1[d * 64 + lane];
    float g = gelu_exact(a);
    float s1 = wsum64(g);
    float s2 = wsum64(g * g);
    float m = s1 * (1.0f / 64.0f);
    float var = s2 * (1.0f / 64.0f) - m * m;
    g = (g - m) * rsqrtf(var + 1e-5f) * lg[lane] + lb[lane];
    gS[wib][lane] = g;
  }
  __syncthreads();
  if (node < NN) {
    float a = b2[lane];
    #pragma unroll 8
    for (int d = 0; d < 64; d++) a += gS[wib][d] * w2[d * 64 + lane];
    h[(size_t)node * 64 + lane] = a;
    hb[(size_t)node * 64 + lane] = __float2bfloat16(a);
  }
}

// ---------------- fused projections via MFMA ----------------
// q is written PRE-SCALED by 0.125 (1/sqrt(C), exact in bf16).
__global__ __launch_bounds__(256) void proj_mfma_kernel(
    const __hip_bfloat16* __restrict__ hbf,
    const __hip_bfloat16* __restrict__ Wb,
    const float* __restrict__ bq, const float* __restrict__ bk,
    const float* __restrict__ bv, const float* __restrict__ bs,
    __hip_bfloat16* __restrict__ q, __hip_bfloat16* __restrict__ k,
    __hip_bfloat16* __restrict__ v, float* __restrict__ xr) {
  const int n0 = blockIdx.x * 64;
  const int w = threadIdx.x >> 6;
  const int l = threadIdx.x & 63;
  const int r = l & 15;
  const int g = l >> 4;
  const int arow = n0 + w * 16 + r;

  bf16x8 A0 = {}, A1 = {};
  if (arow < NN) {
    const bf16x8* ap = reinterpret_cast<const bf16x8*>(hbf + (size_t)arow * 64);
    A0 = ap[g];
    A1 = ap[g + 4];
  }

  const bf16x8* wb = reinterpret_cast<const bf16x8*>(Wb);
  const int nbase = n0 + w * 16 + g * 4;

  for (int ct = 0; ct < 52; ++ct) {
    bf16x8 B0 = wb[(ct * 2 + 0) * 64 + l];
    bf16x8 B1 = wb[(ct * 2 + 1) * 64 + l];
    f32x4 acc = {0.f, 0.f, 0.f, 0.f};
    acc = __builtin_amdgcn_mfma_f32_16x16x32_bf16(A0, B0, acc, 0, 0, 0);
    acc = __builtin_amdgcn_mfma_f32_16x16x32_bf16(A1, B1, acc, 0, 0, 0);
    const int col = ct * 16 + r;   // C/D: col = lane&15, row = (lane>>4)*4 + i
    if (ct < 48) {
      __hip_bfloat16* dstp;
      const float* bias;
      int c;
      float scale = 1.0f;
      if (ct < 16)      { dstp = q; bias = bq; c = col; scale = 0.125f; }
      else if (ct < 32) { dstp = k; bias = bk; c = col - 256; }
      else              { dstp = v; bias = bv; c = col - 512; }
      const float bb = bias[c];
      #pragma unroll
      for (int i = 0; i < 4; ++i) {
        const int node = nbase + i;
        if (node < NN)
          dstp[(size_t)node * 256 + c] = __float2bfloat16((acc[i] + bb) * scale);
      }
    } else {
      const int c = col - 768;
      const float bb = bs[c];
      #pragma unroll
      for (int i = 0; i < 4; ++i) {
        const int node = nbase + i;
        if (node < NN) xr[(size_t)node * 64 + c] = acc[i] + bb;
      }
    }
  }
}

// ---------------- fused edge phase: one wave per dst node over CSR ----------
// agg[n] = (1/4) sum_h [ sum_e ex*(v[src]+eproj) ] / (sum_e ex + 1e-16)
// lane owns channels lane*4..+3 (head = lane>>4). q pre-scaled by 1/sqrt(C).
__global__ __launch_bounds__(256) void edge_fused_kernel(
    const int* __restrict__ offs, const int* __restrict__ src_sorted,
    const float4* __restrict__ ea_sorted,
    const __hip_bfloat16* __restrict__ qb, const __hip_bfloat16* __restrict__ kb,
    const __hip_bfloat16* __restrict__ vb, const float* __restrict__ We,
    float* __restrict__ agg) {
  const int node = (blockIdx.x * 256 + threadIdx.x) >> 6;
  const int lane = threadIdx.x & 63;
  if (node >= NN) return;
  const int c0 = lane * 4;
  const ushort* q = reinterpret_cast<const ushort*>(qb);
  const ushort* k = reinterpret_cast<const ushort*>(kb);
  const ushort* v = reinterpret_cast<const ushort*>(vb);

  const float4 w0 = *reinterpret_cast<const float4*>(We + 0 * 256 + c0);
  const float4 w1 = *reinterpret_cast<const float4*>(We + 1 * 256 + c0);
  const float4 w2 = *reinterpret_cast<const float4*>(We + 2 * 256 + c0);
  const float4 w3 = *reinterpret_cast<const float4*>(We + 3 * 256 + c0);

  const int beg = offs[node];
  const int end = offs[node + 1];
  float qf[4];
  {
    uint2 qu = *reinterpret_cast<const uint2*>(q + (size_t)node * 256 + c0);
    bf4_to_f(qu, qf);
  }
  float m0 = 0.f, m1 = 0.f, m2 = 0.f, m3 = 0.f, sacc = 0.f;
  for (int e = beg; e < end; ++e) {
    const int src = src_sorted[e];
    const float4 av = ea_sorted[e];
    const float eh0 = av.x * w0.x + av.y * w1.x + av.z * w2.x + av.w * w3.x;
    const float eh1 = av.x * w0.y + av.y * w1.y + av.z * w2.y + av.w * w3.y;
    const float eh2 = av.x * w0.z + av.y * w1.z + av.z * w2.z + av.w * w3.z;
    const float eh3 = av.x * w0.w + av.y * w1.w + av.z * w2.w + av.w * w3.w;
    uint2 ku = *reinterpret_cast<const uint2*>(k + (size_t)src * 256 + c0);
    uint2 vu = *reinterpret_cast<const uint2*>(v + (size_t)src * 256 + c0);
    float kf[4], vf[4];
    bf4_to_f(ku, kf);
    bf4_to_f(vu, vf);
    float d = qf[0] * (kf[0] + eh0) + qf[1] * (kf[1] + eh1) +
              qf[2] * (kf[2] + eh2) + qf[3] * (kf[3] + eh3);
    d += __shfl_xor(d, 1, 64);
    d += __shfl_xor(d, 2, 64);
    d += __shfl_xor(d, 4, 64);
    d += __shfl_xor(d, 8, 64);
    const float ex = __expf(d);  // softmax shift-invariance: no max pass needed
    sacc += ex;
    m0 += ex * (vf[0] + eh0);
    m1 += ex * (vf[1] + eh1);
    m2 += ex * (vf[2] + eh2);
    m3 += ex * (vf[3] + eh3);
  }
  const float inv = 0.25f / (sacc + 1e-16f);
  m0 *= inv; m1 *= inv; m2 *= inv; m3 *= inv;
  // mean over heads: lanes {l, l+16, l+32, l+48} share channel (l&15)*4+j
  m0 += __shfl_xor(m0, 16, 64); m0 += __shfl_xor(m0, 32, 64);
  m1 += __shfl_xor(m1, 16, 64); m1 += __shfl_xor(m1, 32, 64);
  m2 += __shfl_xor(m2, 16, 64); m2 += __shfl_xor(m2, 32, 64);
  m3 += __shfl_xor(m3, 16, 64); m3 += __shfl_xor(m3, 32, 64);
  if (lane < 16) {
    float4 o = {m0, m1, m2, m3};
    *reinterpret_cast<float4*>(agg + (size_t)node * 64 + lane * 4) = o;
  }
}

// ---------------- node update: beta-gate + residual + LN ----------------
__global__ __launch_bounds__(256) void node_kernel(
    const float* __restrict__ agg, const float* __restrict__ xr,
    float* __restrict__ h, __hip_bfloat16* __restrict__ hb,
    const float* __restrict__ Wb,
    const float* __restrict__ lg, const float* __restrict__ lb) {
  const int t = blockIdx.x * 256 + threadIdx.x;
  const int node = t >> 6;
  const int lane = t & 63;
  if (node >= NN) return;
  float o = agg[(size_t)node * 64 + lane];
  float x = xr[(size_t)node * 64 + lane];
  float p = o * Wb[lane] + x * Wb[64 + lane] + (o - x) * Wb[128 + lane];
  p = wsum64(p);
  float beta = 1.0f / (1.0f + expf(-p));
  float hn = beta * x + (1.0f - beta) * o;
  float val = h[(size_t)node * 64 + lane] + hn;
  float s1 = wsum64(val);
  float s2 = wsum64(val * val);
  float m = s1 * (1.0f / 64.0f);
  float var = s2 * (1.0f / 64.0f) - m * m;
  float res = (val - m) * rsqrtf(var + 1e-5f) * lg[lane] + lb[lane];
  h[(size_t)node * 64 + lane] = res;
  hb[(size_t)node * 64 + lane] = __float2bfloat16(res);
}

// ---------------- head ----------------
__global__ __launch_bounds__(256) void head_kernel(
    const float* __restrict__ h, const float* __restrict__ w1,
    const float* __restrict__ b1, const float* __restrict__ w2,
    const float* __restrict__ b2, float* __restrict__ out) {
  const int base_node = blockIdx.x * 8;
  const int nib = threadIdx.x >> 5;
  const int c = threadIdx.x & 31;
  __shared__ float hS[8][64];
  #pragma unroll
  for (int i = 0; i < 2; i++) {
    int idx = threadIdx.x + i * 256;
    int nn = idx >> 6, d = idx & 63;
    if (base_node + nn < NN) hS[nn][d] = h[(size_t)(base_node + nn) * 64 + d];
  }
  __syncthreads();
  const int node = base_node + nib;
  if (node < NN) {
    float a = b1[c];
    #pragma unroll 8
    for (int d = 0; d < 64; d++) a += hS[nib][d] * w1[d * 32 + c];
    float g = gelu_exact(a);
    float p0 = g * w2[c * 2 + 0];
    float p1 = g * w2[c * 2 + 1];
    #pragma unroll
    for (int m = 1; m < 32; m <<= 1) {
      p0 += __shfl_xor(p0, m, 64);
      p1 += __shfl_xor(p1, m, 64);
    }
    if (c == 0) {
      out[(size_t)node * 2 + 0] = p0 + b2[0];
      out[(size_t)node * 2 + 1] = p1 + b2[1];
    }
  }
}

extern "C" void kernel_launch(void* const* d_in, const int* in_sizes, int n_in,
                              void* d_out, int out_size, void* d_ws, size_t ws_size,
                              hipStream_t stream) {
  const float* x       = (const float*)d_in[0];
  const int*   ei      = (const int*)d_in[1];
  const float* ea      = (const float*)d_in[2];
  const float* enc_w1  = (const float*)d_in[3];
  const float* enc_b1  = (const float*)d_in[4];
  const float* enc_lng = (const float*)d_in[5];
  const float* enc_lnb = (const float*)d_in[6];
  const float* enc_w2  = (const float*)d_in[7];
  const float* enc_b2  = (const float*)d_in[8];
  const float* Wq      = (const float*)d_in[9];
  const float* bq      = (const float*)d_in[10];
  const float* Wk      = (const float*)d_in[11];
  const float* bk      = (const float*)d_in[12];
  const float* Wv      = (const float*)d_in[13];
  const float* bv      = (const float*)d_in[14];
  const float* We      = (const float*)d_in[15];
  const float* Wskip   = (const float*)d_in[16];
  const float* bskip   = (const float*)d_in[17];
  const float* Wbeta   = (const float*)d_in[18];
  const float* ln_g    = (const float*)d_in[19];
  const float* ln_b    = (const float*)d_in[20];
  const float* hw1     = (const float*)d_in[21];
  const float* hb1     = (const float*)d_in[22];
  const float* hw2     = (const float*)d_in[23];
  const float* hb2     = (const float*)d_in[24];
  float* out = (float*)d_out;

  float* ws  = (float*)d_ws;
  float* h   = ws;                         // NN*64 fp32
  float* xr  = h + (size_t)NN * 64;        // NN*64 fp32
  float* agg = xr + (size_t)NN * 64;       // NN*64 fp32
  float* fend = agg + (size_t)NN * 64;
  __hip_bfloat16* hb = (__hip_bfloat16*)fend;                   // NN*64
  __hip_bfloat16* qb = hb + (size_t)NN * 64;                    // NN*256
  __hip_bfloat16* kb = qb + (size_t)NN * 256;                   // NN*256
  __hip_bfloat16* vb = kb + (size_t)NN * 256;                   // NN*256
  __hip_bfloat16* Wb = vb + (size_t)NN * 256;                   // 2*53248
  int* cnt        = (int*)(Wb + 2 * 53248);                     // NN
  int* offs       = cnt + NN;                                   // NN+1
  int* cursor     = offs + NN + 1;                              // NN
  int* src_sorted = cursor + NN;                                // EE
  float4* ea_sorted = (float4*)(src_sorted + EE + 3);           // EE (16B align)

  // ---- CSR build (layer-independent, once per launch) ----
  hipMemsetAsync(cnt, 0, (size_t)NN * sizeof(int), stream);
  hist_kernel<<<977, 256, 0, stream>>>(ei, cnt);
  scan_kernel<<<1, SCAN_T, 0, stream>>>(cnt, offs, cursor);
  scatter_kernel<<<977, 256, 0, stream>>>(ei, ea, cursor, src_sorted, ea_sorted);

  convert_wb_kernel<<<416, 256, 0, stream>>>(Wq, Wk, Wv, Wskip, Wb);
  enc_kernel<<<12500, 256, 0, stream>>>(x, enc_w1, enc_b1, enc_lng, enc_lnb,
                                        enc_w2, enc_b2, h, hb);

  for (int l = 0; l < 2; l++) {
    proj_mfma_kernel<<<782, 256, 0, stream>>>(
        hb, Wb + (size_t)l * 53248,
        bq + (size_t)l * 256, bk + (size_t)l * 256, bv + (size_t)l * 256,
        bskip + (size_t)l * 64, qb, kb, vb, xr);
    edge_fused_kernel<<<12500, 256, 0, stream>>>(
        offs, src_sorted, ea_sorted, qb, kb, vb, We + (size_t)l * 1024, agg);
    node_kernel<<<12500, 256, 0, stream>>>(agg, xr, h, hb, Wbeta + (size_t)l * 192,
                                           ln_g + (size_t)l * 64,
                                           ln_b + (size_t)l * 64);
  }

  head_kernel<<<6250, 256, 0, stream>>>(h, hw1, hb1, hw2, hb2, out);
}

// Round 10
// 424.447 us; speedup vs baseline: 1.2642x; 1.2642x over previous
//
#include <hip/hip_runtime.h>
#include <hip/hip_bf16.h>
#include <math.h>

#define NN 50000
#define EE 250000
#define SBLK 256
#define NBLK ((NN + SBLK - 1) / SBLK)   // 196

typedef __attribute__((ext_vector_type(8))) short bf16x8;
typedef __attribute__((ext_vector_type(4))) float f32x4;

__device__ __forceinline__ float wsum64(float v) {
  v += __shfl_xor(v, 1, 64);
  v += __shfl_xor(v, 2, 64);
  v += __shfl_xor(v, 4, 64);
  v += __shfl_xor(v, 8, 64);
  v += __shfl_xor(v, 16, 64);
  v += __shfl_xor(v, 32, 64);
  return v;
}

__device__ __forceinline__ int wsum64i(int v) {
  v += __shfl_xor(v, 1, 64);
  v += __shfl_xor(v, 2, 64);
  v += __shfl_xor(v, 4, 64);
  v += __shfl_xor(v, 8, 64);
  v += __shfl_xor(v, 16, 64);
  v += __shfl_xor(v, 32, 64);
  return v;
}

// inclusive wave scan (64 lanes)
__device__ __forceinline__ int wscan_inc(int v, int lane) {
  #pragma unroll
  for (int d = 1; d < 64; d <<= 1) {
    int u = __shfl_up(v, d, 64);
    if (lane >= d) v += u;
  }
  return v;
}

__device__ __forceinline__ float gelu_exact(float a) {
  return 0.5f * a * (1.0f + erff(a * 0.70710678118654752f));
}

// convert 4 packed bf16 (8B as uint2) to 4 floats
__device__ __forceinline__ void bf4_to_f(const uint2 u, float* f) {
  f[0] = __uint_as_float(u.x << 16);
  f[1] = __uint_as_float(u.x & 0xffff0000u);
  f[2] = __uint_as_float(u.y << 16);
  f[3] = __uint_as_float(u.y & 0xffff0000u);
}

// ---------------- weight converter: Wq/Wk/Wv/Wskip -> bf16 MFMA-B-fragment layout
__global__ __launch_bounds__(256) void convert_wb_kernel(
    const float* __restrict__ Wq, const float* __restrict__ Wk,
    const float* __restrict__ Wv, const float* __restrict__ Ws,
    __hip_bfloat16* __restrict__ Wb) {
  const int tid = blockIdx.x * 256 + threadIdx.x;  // 0 .. 2*53248-1
  const int layer = tid / 53248;
  const int rem = tid % 53248;
  const int i = rem & 7;
  const int l = (rem >> 3) & 63;
  const int fct = rem >> 9;        // ct*2 + f
  const int f = fct & 1;
  const int ct = fct >> 1;
  const int col = ct * 16 + (l & 15);
  const int kk = f * 32 + (l >> 4) * 8 + i;
  float val;
  if (col < 256)      val = Wq[(size_t)layer * 16384 + kk * 256 + col];
  else if (col < 512) val = Wk[(size_t)layer * 16384 + kk * 256 + (col - 256)];
  else if (col < 768) val = Wv[(size_t)layer * 16384 + kk * 256 + (col - 512)];
  else                val = Ws[(size_t)layer * 4096 + kk * 64 + (col - 768)];
  Wb[tid] = __float2bfloat16(val);
}

// ---------------- CSR build ----------------
__global__ __launch_bounds__(256) void hist_kernel(const int* __restrict__ ei,
                                                   int* __restrict__ cnt) {
  const int e = blockIdx.x * 256 + threadIdx.x;
  if (e < EE) atomicAdd(&cnt[ei[EE + e]], 1);
}

// two-level scan, stage 1: per-block sums (coalesced)
__global__ __launch_bounds__(256) void bsum_kernel(const int* __restrict__ cnt,
                                                   int* __restrict__ bsum) {
  const int i = blockIdx.x * 256 + threadIdx.x;
  int v = (i < NN) ? cnt[i] : 0;
  v = wsum64i(v);
  __shared__ int ws_[4];
  if ((threadIdx.x & 63) == 0) ws_[threadIdx.x >> 6] = v;
  __syncthreads();
  if (threadIdx.x == 0) bsum[blockIdx.x] = ws_[0] + ws_[1] + ws_[2] + ws_[3];
}

// stage 2: exclusive scan of the 196 block sums (single tiny block)
__global__ __launch_bounds__(256) void bscan_kernel(const int* __restrict__ bsum,
                                                    int* __restrict__ bpre) {
  const int t = threadIdx.x;
  const int lane = t & 63;
  const int w = t >> 6;
  int orig = (t < NBLK) ? bsum[t] : 0;
  int v = wscan_inc(orig, lane);
  __shared__ int wtot[4];
  if (lane == 63) wtot[w] = v;
  __syncthreads();
  int add = 0;
  #pragma unroll
  for (int j = 0; j < 4; j++) if (j < w) add += wtot[j];
  if (t < NBLK) bpre[t] = v + add - orig;  // exclusive prefix
}

// stage 3: in-block exclusive scan + block prefix -> offs & cursor
__global__ __launch_bounds__(256) void scan2_kernel(const int* __restrict__ cnt,
                                                    const int* __restrict__ bpre,
                                                    int* __restrict__ offs,
                                                    int* __restrict__ cursor) {
  const int i = blockIdx.x * 256 + threadIdx.x;
  const int t = threadIdx.x;
  const int lane = t & 63;
  const int w = t >> 6;
  int orig = (i < NN) ? cnt[i] : 0;
  int v = wscan_inc(orig, lane);
  __shared__ int wtot[4];
  if (lane == 63) wtot[w] = v;
  __syncthreads();
  int add = bpre[blockIdx.x];
  #pragma unroll
  for (int j = 0; j < 4; j++) if (j < w) add += wtot[j];
  int ex = v + add - orig;
  if (i < NN) { offs[i] = ex; cursor[i] = ex; }
  if (i == 0) offs[NN] = EE;
}

__global__ __launch_bounds__(256) void scatter_kernel(
    const int* __restrict__ ei, const float* __restrict__ ea,
    int* __restrict__ cursor, int* __restrict__ src_sorted,
    float4* __restrict__ ea_sorted) {
  const int e = blockIdx.x * 256 + threadIdx.x;
  if (e >= EE) return;
  const int dst = ei[EE + e];
  const int pos = atomicAdd(&cursor[dst], 1);
  src_sorted[pos] = ei[e];
  ea_sorted[pos] = reinterpret_cast<const float4*>(ea)[e];
}

// ---------------- encoder ----------------
__global__ __launch_bounds__(256) void enc_kernel(
    const float* __restrict__ x, const float* __restrict__ w1,
    const float* __restrict__ b1, const float* __restrict__ lg,
    const float* __restrict__ lb, const float* __restrict__ w2,
    const float* __restrict__ b2, float* __restrict__ h,
    __hip_bfloat16* __restrict__ hb) {
  const int t = blockIdx.x * 256 + threadIdx.x;
  const int node = t >> 6;
  const int lane = t & 63;
  const int wib = (threadIdx.x >> 6);
  __shared__ float gS[4][64];
  if (node < NN) {
    float a = b1[lane];
    #pragma unroll
    for (int d = 0; d < 6; d++) a += x[(size_t)node * 6 + d] * w1[d * 64 + lane];
    float g = gelu_exact(a);
    float s1 = wsum64(g);
    float s2 = wsum64(g * g);
    float m = s1 * (1.0f / 64.0f);
    float var = s2 * (1.0f / 64.0f) - m * m;
    g = (g - m) * rsqrtf(var + 1e-5f) * lg[lane] + lb[lane];
    gS[wib][lane] = g;
  }
  __syncthreads();
  if (node < NN) {
    float a = b2[lane];
    #pragma unroll 8
    for (int d = 0; d < 64; d++) a += gS[wib][d] * w2[d * 64 + lane];
    h[(size_t)node * 64 + lane] = a;
    hb[(size_t)node * 64 + lane] = __float2bfloat16(a);
  }
}

// ---------------- fused projections via MFMA ----------------
// q is written PRE-SCALED by 0.125 (1/sqrt(C), exact in bf16).
__global__ __launch_bounds__(256) void proj_mfma_kernel(
    const __hip_bfloat16* __restrict__ hbf,
    const __hip_bfloat16* __restrict__ Wb,
    const float* __restrict__ bq, const float* __restrict__ bk,
    const float* __restrict__ bv, const float* __restrict__ bs,
    __hip_bfloat16* __restrict__ q, __hip_bfloat16* __restrict__ k,
    __hip_bfloat16* __restrict__ v, float* __restrict__ xr) {
  const int n0 = blockIdx.x * 64;
  const int w = threadIdx.x >> 6;
  const int l = threadIdx.x & 63;
  const int r = l & 15;
  const int g = l >> 4;
  const int arow = n0 + w * 16 + r;

  bf16x8 A0 = {}, A1 = {};
  if (arow < NN) {
    const bf16x8* ap = reinterpret_cast<const bf16x8*>(hbf + (size_t)arow * 64);
    A0 = ap[g];
    A1 = ap[g + 4];
  }

  const bf16x8* wb = reinterpret_cast<const bf16x8*>(Wb);
  const int nbase = n0 + w * 16 + g * 4;

  for (int ct = 0; ct < 52; ++ct) {
    bf16x8 B0 = wb[(ct * 2 + 0) * 64 + l];
    bf16x8 B1 = wb[(ct * 2 + 1) * 64 + l];
    f32x4 acc = {0.f, 0.f, 0.f, 0.f};
    acc = __builtin_amdgcn_mfma_f32_16x16x32_bf16(A0, B0, acc, 0, 0, 0);
    acc = __builtin_amdgcn_mfma_f32_16x16x32_bf16(A1, B1, acc, 0, 0, 0);
    const int col = ct * 16 + r;   // C/D: col = lane&15, row = (lane>>4)*4 + i
    if (ct < 48) {
      __hip_bfloat16* dstp;
      const float* bias;
      int c;
      float scale = 1.0f;
      if (ct < 16)      { dstp = q; bias = bq; c = col; scale = 0.125f; }
      else if (ct < 32) { dstp = k; bias = bk; c = col - 256; }
      else              { dstp = v; bias = bv; c = col - 512; }
      const float bb = bias[c];
      #pragma unroll
      for (int i = 0; i < 4; ++i) {
        const int node = nbase + i;
        if (node < NN)
          dstp[(size_t)node * 256 + c] = __float2bfloat16((acc[i] + bb) * scale);
      }
    } else {
      const int c = col - 768;
      const float bb = bs[c];
      #pragma unroll
      for (int i = 0; i < 4; ++i) {
        const int node = nbase + i;
        if (node < NN) xr[(size_t)node * 64 + c] = acc[i] + bb;
      }
    }
  }
}

// ---------------- fused edge phase: one wave per dst node over CSR ----------
// agg[n] = (1/4) sum_h [ sum_e ex*(v[src]+eproj) ] / (sum_e ex + 1e-16)
// lane owns channels lane*4..+3 (head = lane>>4). q pre-scaled by 1/sqrt(C).
__global__ __launch_bounds__(256) void edge_fused_kernel(
    const int* __restrict__ offs, const int* __restrict__ src_sorted,
    const float4* __restrict__ ea_sorted,
    const __hip_bfloat16* __restrict__ qb, const __hip_bfloat16* __restrict__ kb,
    const __hip_bfloat16* __restrict__ vb, const float* __restrict__ We,
    float* __restrict__ agg) {
  const int node = (blockIdx.x * 256 + threadIdx.x) >> 6;
  const int lane = threadIdx.x & 63;
  if (node >= NN) return;
  const int c0 = lane * 4;
  const ushort* q = reinterpret_cast<const ushort*>(qb);
  const ushort* k = reinterpret_cast<const ushort*>(kb);
  const ushort* v = reinterpret_cast<const ushort*>(vb);

  const float4 w0 = *reinterpret_cast<const float4*>(We + 0 * 256 + c0);
  const float4 w1 = *reinterpret_cast<const float4*>(We + 1 * 256 + c0);
  const float4 w2 = *reinterpret_cast<const float4*>(We + 2 * 256 + c0);
  const float4 w3 = *reinterpret_cast<const float4*>(We + 3 * 256 + c0);

  const int beg = offs[node];
  const int end = offs[node + 1];
  float qf[4];
  {
    uint2 qu = *reinterpret_cast<const uint2*>(q + (size_t)node * 256 + c0);
    bf4_to_f(qu, qf);
  }
  float m0 = 0.f, m1 = 0.f, m2 = 0.f, m3 = 0.f, sacc = 0.f;
  for (int e = beg; e < end; ++e) {
    const int src = src_sorted[e];
    const float4 av = ea_sorted[e];
    const float eh0 = av.x * w0.x + av.y * w1.x + av.z * w2.x + av.w * w3.x;
    const float eh1 = av.x * w0.y + av.y * w1.y + av.z * w2.y + av.w * w3.y;
    const float eh2 = av.x * w0.z + av.y * w1.z + av.z * w2.z + av.w * w3.z;
    const float eh3 = av.x * w0.w + av.y * w1.w + av.z * w2.w + av.w * w3.w;
    uint2 ku = *reinterpret_cast<const uint2*>(k + (size_t)src * 256 + c0);
    uint2 vu = *reinterpret_cast<const uint2*>(v + (size_t)src * 256 + c0);
    float kf[4], vf[4];
    bf4_to_f(ku, kf);
    bf4_to_f(vu, vf);
    float d = qf[0] * (kf[0] + eh0) + qf[1] * (kf[1] + eh1) +
              qf[2] * (kf[2] + eh2) + qf[3] * (kf[3] + eh3);
    d += __shfl_xor(d, 1, 64);
    d += __shfl_xor(d, 2, 64);
    d += __shfl_xor(d, 4, 64);
    d += __shfl_xor(d, 8, 64);
    const float ex = __expf(d);  // softmax shift-invariance: no max pass needed
    sacc += ex;
    m0 += ex * (vf[0] + eh0);
    m1 += ex * (vf[1] + eh1);
    m2 += ex * (vf[2] + eh2);
    m3 += ex * (vf[3] + eh3);
  }
  const float inv = 0.25f / (sacc + 1e-16f);
  m0 *= inv; m1 *= inv; m2 *= inv; m3 *= inv;
  // mean over heads: lanes {l, l+16, l+32, l+48} share channel (l&15)*4+j
  m0 += __shfl_xor(m0, 16, 64); m0 += __shfl_xor(m0, 32, 64);
  m1 += __shfl_xor(m1, 16, 64); m1 += __shfl_xor(m1, 32, 64);
  m2 += __shfl_xor(m2, 16, 64); m2 += __shfl_xor(m2, 32, 64);
  m3 += __shfl_xor(m3, 16, 64); m3 += __shfl_xor(m3, 32, 64);
  if (lane < 16) {
    float4 o = {m0, m1, m2, m3};
    *reinterpret_cast<float4*>(agg + (size_t)node * 64 + lane * 4) = o;
  }
}

// ---------------- node update: beta-gate + residual + LN ----------------
__global__ __launch_bounds__(256) void node_kernel(
    const float* __restrict__ agg, const float* __restrict__ xr,
    float* __restrict__ h, __hip_bfloat16* __restrict__ hb,
    const float* __restrict__ Wb,
    const float* __restrict__ lg, const float* __restrict__ lb) {
  const int t = blockIdx.x * 256 + threadIdx.x;
  const int node = t >> 6;
  const int lane = t & 63;
  if (node >= NN) return;
  float o = agg[(size_t)node * 64 + lane];
  float x = xr[(size_t)node * 64 + lane];
  float p = o * Wb[lane] + x * Wb[64 + lane] + (o - x) * Wb[128 + lane];
  p = wsum64(p);
  float beta = 1.0f / (1.0f + expf(-p));
  float hn = beta * x + (1.0f - beta) * o;
  float val = h[(size_t)node * 64 + lane] + hn;
  float s1 = wsum64(val);
  float s2 = wsum64(val * val);
  float m = s1 * (1.0f / 64.0f);
  float var = s2 * (1.0f / 64.0f) - m * m;
  float res = (val - m) * rsqrtf(var + 1e-5f) * lg[lane] + lb[lane];
  h[(size_t)node * 64 + lane] = res;
  hb[(size_t)node * 64 + lane] = __float2bfloat16(res);
}

// ---------------- head ----------------
__global__ __launch_bounds__(256) void head_kernel(
    const float* __restrict__ h, const float* __restrict__ w1,
    const float* __restrict__ b1, const float* __restrict__ w2,
    const float* __restrict__ b2, float* __restrict__ out) {
  const int base_node = blockIdx.x * 8;
  const int nib = threadIdx.x >> 5;
  const int c = threadIdx.x & 31;
  __shared__ float hS[8][64];
  #pragma unroll
  for (int i = 0; i < 2; i++) {
    int idx = threadIdx.x + i * 256;
    int nn = idx >> 6, d = idx & 63;
    if (base_node + nn < NN) hS[nn][d] = h[(size_t)(base_node + nn) * 64 + d];
  }
  __syncthreads();
  const int node = base_node + nib;
  if (node < NN) {
    float a = b1[c];
    #pragma unroll 8
    for (int d = 0; d < 64; d++) a += hS[nib][d] * w1[d * 32 + c];
    float g = gelu_exact(a);
    float p0 = g * w2[c * 2 + 0];
    float p1 = g * w2[c * 2 + 1];
    #pragma unroll
    for (int m = 1; m < 32; m <<= 1) {
      p0 += __shfl_xor(p0, m, 64);
      p1 += __shfl_xor(p1, m, 64);
    }
    if (c == 0) {
      out[(size_t)node * 2 + 0] = p0 + b2[0];
      out[(size_t)node * 2 + 1] = p1 + b2[1];
    }
  }
}

extern "C" void kernel_launch(void* const* d_in, const int* in_sizes, int n_in,
                              void* d_out, int out_size, void* d_ws, size_t ws_size,
                              hipStream_t stream) {
  const float* x       = (const float*)d_in[0];
  const int*   ei      = (const int*)d_in[1];
  const float* ea      = (const float*)d_in[2];
  const float* enc_w1  = (const float*)d_in[3];
  const float* enc_b1  = (const float*)d_in[4];
  const float* enc_lng = (const float*)d_in[5];
  const float* enc_lnb = (const float*)d_in[6];
  const float* enc_w2  = (const float*)d_in[7];
  const float* enc_b2  = (const float*)d_in[8];
  const float* Wq      = (const float*)d_in[9];
  const float* bq      = (const float*)d_in[10];
  const float* Wk      = (const float*)d_in[11];
  const float* bk      = (const float*)d_in[12];
  const float* Wv      = (const float*)d_in[13];
  const float* bv      = (const float*)d_in[14];
  const float* We      = (const float*)d_in[15];
  const float* Wskip   = (const float*)d_in[16];
  const float* bskip   = (const float*)d_in[17];
  const float* Wbeta   = (const float*)d_in[18];
  const float* ln_g    = (const float*)d_in[19];
  const float* ln_b    = (const float*)d_in[20];
  const float* hw1     = (const float*)d_in[21];
  const float* hb1     = (const float*)d_in[22];
  const float* hw2     = (const float*)d_in[23];
  const float* hb2     = (const float*)d_in[24];
  float* out = (float*)d_out;

  float* ws  = (float*)d_ws;
  float* h   = ws;                         // NN*64 fp32
  float* xr  = h + (size_t)NN * 64;        // NN*64 fp32
  float* agg = xr + (size_t)NN * 64;       // NN*64 fp32
  float* fend = agg + (size_t)NN * 64;
  __hip_bfloat16* hb = (__hip_bfloat16*)fend;                   // NN*64
  __hip_bfloat16* qb = hb + (size_t)NN * 64;                    // NN*256
  __hip_bfloat16* kb = qb + (size_t)NN * 256;                   // NN*256
  __hip_bfloat16* vb = kb + (size_t)NN * 256;                   // NN*256
  __hip_bfloat16* Wb = vb + (size_t)NN * 256;                   // 2*53248
  int* cnt        = (int*)(Wb + 2 * 53248);                     // NN
  int* offs       = cnt + NN;                                   // NN+1
  int* cursor     = offs + NN + 1;                              // NN
  int* bsum       = cursor + NN;                                // NBLK
  int* bpre       = bsum + NBLK;                                // NBLK
  int* src_sorted = bpre + NBLK;                                // EE
  float4* ea_sorted = (float4*)(src_sorted + EE + 3);           // EE (16B align)

  // ---- CSR build (layer-independent, once per launch) ----
  hipMemsetAsync(cnt, 0, (size_t)NN * sizeof(int), stream);
  hist_kernel<<<977, 256, 0, stream>>>(ei, cnt);
  bsum_kernel<<<NBLK, 256, 0, stream>>>(cnt, bsum);
  bscan_kernel<<<1, 256, 0, stream>>>(bsum, bpre);
  scan2_kernel<<<NBLK, 256, 0, stream>>>(cnt, bpre, offs, cursor);
  scatter_kernel<<<977, 256, 0, stream>>>(ei, ea, cursor, src_sorted, ea_sorted);

  convert_wb_kernel<<<416, 256, 0, stream>>>(Wq, Wk, Wv, Wskip, Wb);
  enc_kernel<<<12500, 256, 0, stream>>>(x, enc_w1, enc_b1, enc_lng, enc_lnb,
                                        enc_w2, enc_b2, h, hb);

  for (int l = 0; l < 2; l++) {
    proj_mfma_kernel<<<782, 256, 0, stream>>>(
        hb, Wb + (size_t)l * 53248,
        bq + (size_t)l * 256, bk + (size_t)l * 256, bv + (size_t)l * 256,
        bskip + (size_t)l * 64, qb, kb, vb, xr);
    edge_fused_kernel<<<12500, 256, 0, stream>>>(
        offs, src_sorted, ea_sorted, qb, kb, vb, We + (size_t)l * 1024, agg);
    node_kernel<<<12500, 256, 0, stream>>>(agg, xr, h, hb, Wbeta + (size_t)l * 192,
                                           ln_g + (size_t)l * 64,
                                           ln_b + (size_t)l * 64);
  }

  head_kernel<<<6250, 256, 0, stream>>>(h, hw1, hb1, hw2, hb2, out);
}

// Round 11
// 414.017 us; speedup vs baseline: 1.2960x; 1.0252x over previous
//
#include <hip/hip_runtime.h>
#include <hip/hip_bf16.h>
#include <math.h>

#define NN 50000
#define EE 250000
#define SBLK 256
#define NBLK ((NN + SBLK - 1) / SBLK)   // 196

typedef __attribute__((ext_vector_type(8))) short bf16x8;
typedef __attribute__((ext_vector_type(4))) float f32x4;

__device__ __forceinline__ float wsum64(float v) {
  v += __shfl_xor(v, 1, 64);
  v += __shfl_xor(v, 2, 64);
  v += __shfl_xor(v, 4, 64);
  v += __shfl_xor(v, 8, 64);
  v += __shfl_xor(v, 16, 64);
  v += __shfl_xor(v, 32, 64);
  return v;
}

__device__ __forceinline__ int wsum64i(int v) {
  v += __shfl_xor(v, 1, 64);
  v += __shfl_xor(v, 2, 64);
  v += __shfl_xor(v, 4, 64);
  v += __shfl_xor(v, 8, 64);
  v += __shfl_xor(v, 16, 64);
  v += __shfl_xor(v, 32, 64);
  return v;
}

// inclusive wave scan (64 lanes)
__device__ __forceinline__ int wscan_inc(int v, int lane) {
  #pragma unroll
  for (int d = 1; d < 64; d <<= 1) {
    int u = __shfl_up(v, d, 64);
    if (lane >= d) v += u;
  }
  return v;
}

__device__ __forceinline__ float gelu_exact(float a) {
  return 0.5f * a * (1.0f + erff(a * 0.70710678118654752f));
}

__device__ __forceinline__ ushort f2bf(float f) {
  __hip_bfloat16 h = __float2bfloat16(f);
  return *reinterpret_cast<ushort*>(&h);
}

// convert 4 packed bf16 (8B as uint2) to 4 floats
__device__ __forceinline__ void bf4_to_f(const uint2 u, float* f) {
  f[0] = __uint_as_float(u.x << 16);
  f[1] = __uint_as_float(u.x & 0xffff0000u);
  f[2] = __uint_as_float(u.y << 16);
  f[3] = __uint_as_float(u.y & 0xffff0000u);
}

// ---------------- weight converter: Wq/Wk/Wv/Wskip -> bf16 MFMA-fragment layout
// lane l, reg i of tile (ct,f): element W[k][col], col=ct*16+(l&15), k=f*32+(l>>4)*8+i
// (usable as B-frag with col=N, or as A-frag giving A[m][k]=W^T tile)
__global__ __launch_bounds__(256) void convert_wb_kernel(
    const float* __restrict__ Wq, const float* __restrict__ Wk,
    const float* __restrict__ Wv, const float* __restrict__ Ws,
    __hip_bfloat16* __restrict__ Wb) {
  const int tid = blockIdx.x * 256 + threadIdx.x;  // 0 .. 2*53248-1
  const int layer = tid / 53248;
  const int rem = tid % 53248;
  const int i = rem & 7;
  const int l = (rem >> 3) & 63;
  const int fct = rem >> 9;        // ct*2 + f
  const int f = fct & 1;
  const int ct = fct >> 1;
  const int col = ct * 16 + (l & 15);
  const int kk = f * 32 + (l >> 4) * 8 + i;
  float val;
  if (col < 256)      val = Wq[(size_t)layer * 16384 + kk * 256 + col];
  else if (col < 512) val = Wk[(size_t)layer * 16384 + kk * 256 + (col - 256)];
  else if (col < 768) val = Wv[(size_t)layer * 16384 + kk * 256 + (col - 512)];
  else                val = Ws[(size_t)layer * 4096 + kk * 64 + (col - 768)];
  Wb[tid] = __float2bfloat16(val);
}

// ---------------- CSR build ----------------
__global__ __launch_bounds__(256) void hist_kernel(const int* __restrict__ ei,
                                                   int* __restrict__ cnt) {
  const int e = blockIdx.x * 256 + threadIdx.x;
  if (e < EE) atomicAdd(&cnt[ei[EE + e]], 1);
}

// two-level scan, stage 1: per-block sums (coalesced)
__global__ __launch_bounds__(256) void bsum_kernel(const int* __restrict__ cnt,
                                                   int* __restrict__ bsum) {
  const int i = blockIdx.x * 256 + threadIdx.x;
  int v = (i < NN) ? cnt[i] : 0;
  v = wsum64i(v);
  __shared__ int ws_[4];
  if ((threadIdx.x & 63) == 0) ws_[threadIdx.x >> 6] = v;
  __syncthreads();
  if (threadIdx.x == 0) bsum[blockIdx.x] = ws_[0] + ws_[1] + ws_[2] + ws_[3];
}

// stage 2: exclusive scan of the 196 block sums (single tiny block)
__global__ __launch_bounds__(256) void bscan_kernel(const int* __restrict__ bsum,
                                                    int* __restrict__ bpre) {
  const int t = threadIdx.x;
  const int lane = t & 63;
  const int w = t >> 6;
  int orig = (t < NBLK) ? bsum[t] : 0;
  int v = wscan_inc(orig, lane);
  __shared__ int wtot[4];
  if (lane == 63) wtot[w] = v;
  __syncthreads();
  int add = 0;
  #pragma unroll
  for (int j = 0; j < 4; j++) if (j < w) add += wtot[j];
  if (t < NBLK) bpre[t] = v + add - orig;  // exclusive prefix
}

// stage 3: in-block exclusive scan + block prefix -> offs & cursor
__global__ __launch_bounds__(256) void scan2_kernel(const int* __restrict__ cnt,
                                                    const int* __restrict__ bpre,
                                                    int* __restrict__ offs,
                                                    int* __restrict__ cursor) {
  const int i = blockIdx.x * 256 + threadIdx.x;
  const int t = threadIdx.x;
  const int lane = t & 63;
  const int w = t >> 6;
  int orig = (i < NN) ? cnt[i] : 0;
  int v = wscan_inc(orig, lane);
  __shared__ int wtot[4];
  if (lane == 63) wtot[w] = v;
  __syncthreads();
  int add = bpre[blockIdx.x];
  #pragma unroll
  for (int j = 0; j < 4; j++) if (j < w) add += wtot[j];
  int ex = v + add - orig;
  if (i < NN) { offs[i] = ex; cursor[i] = ex; }
  if (i == 0) offs[NN] = EE;
}

__global__ __launch_bounds__(256) void scatter_kernel(
    const int* __restrict__ ei, const float* __restrict__ ea,
    int* __restrict__ cursor, int* __restrict__ src_sorted,
    float4* __restrict__ ea_sorted) {
  const int e = blockIdx.x * 256 + threadIdx.x;
  if (e >= EE) return;
  const int dst = ei[EE + e];
  const int pos = atomicAdd(&cursor[dst], 1);
  src_sorted[pos] = ei[e];
  ea_sorted[pos] = reinterpret_cast<const float4*>(ea)[e];
}

// ---------------- encoder ----------------
__global__ __launch_bounds__(256) void enc_kernel(
    const float* __restrict__ x, const float* __restrict__ w1,
    const float* __restrict__ b1, const float* __restrict__ lg,
    const float* __restrict__ lb, const float* __restrict__ w2,
    const float* __restrict__ b2, float* __restrict__ h,
    __hip_bfloat16* __restrict__ hb) {
  const int t = blockIdx.x * 256 + threadIdx.x;
  const int node = t >> 6;
  const int lane = t & 63;
  const int wib = (threadIdx.x >> 6);
  __shared__ float gS[4][64];
  if (node < NN) {
    float a = b1[lane];
    #pragma unroll
    for (int d = 0; d < 6; d++) a += x[(size_t)node * 6 + d] * w1[d * 64 + lane];
    float g = gelu_exact(a);
    float s1 = wsum64(g);
    float s2 = wsum64(g * g);
    float m = s1 * (1.0f / 64.0f);
    float var = s2 * (1.0f / 64.0f) - m * m;
    g = (g - m) * rsqrtf(var + 1e-5f) * lg[lane] + lb[lane];
    gS[wib][lane] = g;
  }
  __syncthreads();
  if (node < NN) {
    float a = b2[lane];
    #pragma unroll 8
    for (int d = 0; d < 64; d++) a += gS[wib][d] * w2[d * 64 + lane];
    h[(size_t)node * 64 + lane] = a;
    hb[(size_t)node * 64 + lane] = __float2bfloat16(a);
  }
}

// ---------------- fused projections via MFMA (operand-swapped) ----------------
// acc = mfma(Wfrag, hfrag): D col = node (lane&15), D rows = 4 consecutive
// weight-cols (lane>>4)*4+i  ->  one 8B bf16x4 store (or 16B f32x4 for xr) per tile.
// q is written PRE-SCALED by 0.125 (1/sqrt(C), exact in bf16).
__global__ __launch_bounds__(256) void proj_mfma_kernel(
    const __hip_bfloat16* __restrict__ hbf,
    const __hip_bfloat16* __restrict__ Wb,
    const float* __restrict__ bq, const float* __restrict__ bk,
    const float* __restrict__ bv, const float* __restrict__ bs,
    __hip_bfloat16* __restrict__ q, __hip_bfloat16* __restrict__ k,
    __hip_bfloat16* __restrict__ v, float* __restrict__ xr) {
  const int n0 = blockIdx.x * 64;
  const int w = threadIdx.x >> 6;
  const int l = threadIdx.x & 63;
  const int r = l & 15;
  const int g = l >> 4;
  const int node = n0 + w * 16 + r;   // this lane's node (input row AND output col)
  const int cg = g * 4;               // first of 4 weight-cols this lane owns
  const bool in = (node < NN);

  bf16x8 A0 = {}, A1 = {};
  if (in) {
    const bf16x8* ap = reinterpret_cast<const bf16x8*>(hbf + (size_t)node * 64);
    A0 = ap[g];        // k = g*8 .. g*8+7
    A1 = ap[g + 4];    // k = 32 + g*8 ..
  }

  const bf16x8* wb = reinterpret_cast<const bf16x8*>(Wb);

  for (int ct = 0; ct < 52; ++ct) {
    bf16x8 B0 = wb[(ct * 2 + 0) * 64 + l];
    bf16x8 B1 = wb[(ct * 2 + 1) * 64 + l];
    f32x4 acc = {0.f, 0.f, 0.f, 0.f};
    // SWAPPED: weights as A (=> W^T tile), h as B. D[wcol][node].
    acc = __builtin_amdgcn_mfma_f32_16x16x32_bf16(B0, A0, acc, 0, 0, 0);
    acc = __builtin_amdgcn_mfma_f32_16x16x32_bf16(B1, A1, acc, 0, 0, 0);
    if (!in) continue;
    if (ct < 48) {
      __hip_bfloat16* dstp;
      const float* bias;
      int cb;
      float scale = 1.0f;
      if (ct < 16)      { dstp = q; bias = bq; cb = ct * 16 + cg; scale = 0.125f; }
      else if (ct < 32) { dstp = k; bias = bk; cb = (ct - 16) * 16 + cg; }
      else              { dstp = v; bias = bv; cb = (ct - 32) * 16 + cg; }
      const float4 bb = *reinterpret_cast<const float4*>(bias + cb);
      uint2 pk;
      pk.x = (uint)f2bf((acc[0] + bb.x) * scale) |
             ((uint)f2bf((acc[1] + bb.y) * scale) << 16);
      pk.y = (uint)f2bf((acc[2] + bb.z) * scale) |
             ((uint)f2bf((acc[3] + bb.w) * scale) << 16);
      *reinterpret_cast<uint2*>(dstp + (size_t)node * 256 + cb) = pk;
    } else {
      const int cb = (ct - 48) * 16 + cg;
      const float4 bb = *reinterpret_cast<const float4*>(bs + cb);
      float4 o = {acc[0] + bb.x, acc[1] + bb.y, acc[2] + bb.z, acc[3] + bb.w};
      *reinterpret_cast<float4*>(xr + (size_t)node * 64 + cb) = o;
    }
  }
}

// ---------------- fused edge phase: one wave per dst node over CSR ----------
// agg[n] = (1/4) sum_h [ sum_e ex*(v[src]+eproj) ] / (sum_e ex + 1e-16)
// lane owns channels lane*4..+3 (head = lane>>4). q pre-scaled by 1/sqrt(C).
__global__ __launch_bounds__(256) void edge_fused_kernel(
    const int* __restrict__ offs, const int* __restrict__ src_sorted,
    const float4* __restrict__ ea_sorted,
    const __hip_bfloat16* __restrict__ qb, const __hip_bfloat16* __restrict__ kb,
    const __hip_bfloat16* __restrict__ vb, const float* __restrict__ We,
    float* __restrict__ agg) {
  const int node = (blockIdx.x * 256 + threadIdx.x) >> 6;
  const int lane = threadIdx.x & 63;
  if (node >= NN) return;
  const int c0 = lane * 4;
  const ushort* q = reinterpret_cast<const ushort*>(qb);
  const ushort* k = reinterpret_cast<const ushort*>(kb);
  const ushort* v = reinterpret_cast<const ushort*>(vb);

  const float4 w0 = *reinterpret_cast<const float4*>(We + 0 * 256 + c0);
  const float4 w1 = *reinterpret_cast<const float4*>(We + 1 * 256 + c0);
  const float4 w2 = *reinterpret_cast<const float4*>(We + 2 * 256 + c0);
  const float4 w3 = *reinterpret_cast<const float4*>(We + 3 * 256 + c0);

  const int beg = offs[node];
  const int end = offs[node + 1];
  float qf[4];
  {
    uint2 qu = *reinterpret_cast<const uint2*>(q + (size_t)node * 256 + c0);
    bf4_to_f(qu, qf);
  }
  float m0 = 0.f, m1 = 0.f, m2 = 0.f, m3 = 0.f, sacc = 0.f;
  for (int e = beg; e < end; ++e) {
    const int src = src_sorted[e];
    const float4 av = ea_sorted[e];
    const float eh0 = av.x * w0.x + av.y * w1.x + av.z * w2.x + av.w * w3.x;
    const float eh1 = av.x * w0.y + av.y * w1.y + av.z * w2.y + av.w * w3.y;
    const float eh2 = av.x * w0.z + av.y * w1.z + av.z * w2.z + av.w * w3.z;
    const float eh3 = av.x * w0.w + av.y * w1.w + av.z * w2.w + av.w * w3.w;
    uint2 ku = *reinterpret_cast<const uint2*>(k + (size_t)src * 256 + c0);
    uint2 vu = *reinterpret_cast<const uint2*>(v + (size_t)src * 256 + c0);
    float kf[4], vf[4];
    bf4_to_f(ku, kf);
    bf4_to_f(vu, vf);
    float d = qf[0] * (kf[0] + eh0) + qf[1] * (kf[1] + eh1) +
              qf[2] * (kf[2] + eh2) + qf[3] * (kf[3] + eh3);
    d += __shfl_xor(d, 1, 64);
    d += __shfl_xor(d, 2, 64);
    d += __shfl_xor(d, 4, 64);
    d += __shfl_xor(d, 8, 64);
    const float ex = __expf(d);  // softmax shift-invariance: no max pass needed
    sacc += ex;
    m0 += ex * (vf[0] + eh0);
    m1 += ex * (vf[1] + eh1);
    m2 += ex * (vf[2] + eh2);
    m3 += ex * (vf[3] + eh3);
  }
  const float inv = 0.25f / (sacc + 1e-16f);
  m0 *= inv; m1 *= inv; m2 *= inv; m3 *= inv;
  // mean over heads: lanes {l, l+16, l+32, l+48} share channel (l&15)*4+j
  m0 += __shfl_xor(m0, 16, 64); m0 += __shfl_xor(m0, 32, 64);
  m1 += __shfl_xor(m1, 16, 64); m1 += __shfl_xor(m1, 32, 64);
  m2 += __shfl_xor(m2, 16, 64); m2 += __shfl_xor(m2, 32, 64);
  m3 += __shfl_xor(m3, 16, 64); m3 += __shfl_xor(m3, 32, 64);
  if (lane < 16) {
    float4 o = {m0, m1, m2, m3};
    *reinterpret_cast<float4*>(agg + (size_t)node * 64 + lane * 4) = o;
  }
}

// ---------------- node update: beta-gate + residual + LN ----------------
__global__ __launch_bounds__(256) void node_kernel(
    const float* __restrict__ agg, const float* __restrict__ xr,
    float* __restrict__ h, __hip_bfloat16* __restrict__ hb,
    const float* __restrict__ Wb,
    const float* __restrict__ lg, const float* __restrict__ lb) {
  const int t = blockIdx.x * 256 + threadIdx.x;
  const int node = t >> 6;
  const int lane = t & 63;
  if (node >= NN) return;
  float o = agg[(size_t)node * 64 + lane];
  float x = xr[(size_t)node * 64 + lane];
  float p = o * Wb[lane] + x * Wb[64 + lane] + (o - x) * Wb[128 + lane];
  p = wsum64(p);
  float beta = 1.0f / (1.0f + expf(-p));
  float hn = beta * x + (1.0f - beta) * o;
  float val = h[(size_t)node * 64 + lane] + hn;
  float s1 = wsum64(val);
  float s2 = wsum64(val * val);
  float m = s1 * (1.0f / 64.0f);
  float var = s2 * (1.0f / 64.0f) - m * m;
  float res = (val - m) * rsqrtf(var + 1e-5f) * lg[lane] + lb[lane];
  h[(size_t)node * 64 + lane] = res;
  hb[(size_t)node * 64 + lane] = __float2bfloat16(res);
}

// ---------------- head ----------------
__global__ __launch_bounds__(256) void head_kernel(
    const float* __restrict__ h, const float* __restrict__ w1,
    const float* __restrict__ b1, const float* __restrict__ w2,
    const float* __restrict__ b2, float* __restrict__ out) {
  const int base_node = blockIdx.x * 8;
  const int nib = threadIdx.x >> 5;
  const int c = threadIdx.x & 31;
  __shared__ float hS[8][64];
  #pragma unroll
  for (int i = 0; i < 2; i++) {
    int idx = threadIdx.x + i * 256;
    int nn = idx >> 6, d = idx & 63;
    if (base_node + nn < NN) hS[nn][d] = h[(size_t)(base_node + nn) * 64 + d];
  }
  __syncthreads();
  const int node = base_node + nib;
  if (node < NN) {
    float a = b1[c];
    #pragma unroll 8
    for (int d = 0; d < 64; d++) a += hS[nib][d] * w1[d * 32 + c];
    float g = gelu_exact(a);
    float p0 = g * w2[c * 2 + 0];
    float p1 = g * w2[c * 2 + 1];
    #pragma unroll
    for (int m = 1; m < 32; m <<= 1) {
      p0 += __shfl_xor(p0, m, 64);
      p1 += __shfl_xor(p1, m, 64);
    }
    if (c == 0) {
      out[(size_t)node * 2 + 0] = p0 + b2[0];
      out[(size_t)node * 2 + 1] = p1 + b2[1];
    }
  }
}

extern "C" void kernel_launch(void* const* d_in, const int* in_sizes, int n_in,
                              void* d_out, int out_size, void* d_ws, size_t ws_size,
                              hipStream_t stream) {
  const float* x       = (const float*)d_in[0];
  const int*   ei      = (const int*)d_in[1];
  const float* ea      = (const float*)d_in[2];
  const float* enc_w1  = (const float*)d_in[3];
  const float* enc_b1  = (const float*)d_in[4];
  const float* enc_lng = (const float*)d_in[5];
  const float* enc_lnb = (const float*)d_in[6];
  const float* enc_w2  = (const float*)d_in[7];
  const float* enc_b2  = (const float*)d_in[8];
  const float* Wq      = (const float*)d_in[9];
  const float* bq      = (const float*)d_in[10];
  const float* Wk      = (const float*)d_in[11];
  const float* bk      = (const float*)d_in[12];
  const float* Wv      = (const float*)d_in[13];
  const float* bv      = (const float*)d_in[14];
  const float* We      = (const float*)d_in[15];
  const float* Wskip   = (const float*)d_in[16];
  const float* bskip   = (const float*)d_in[17];
  const float* Wbeta   = (const float*)d_in[18];
  const float* ln_g    = (const float*)d_in[19];
  const float* ln_b    = (const float*)d_in[20];
  const float* hw1     = (const float*)d_in[21];
  const float* hb1     = (const float*)d_in[22];
  const float* hw2     = (const float*)d_in[23];
  const float* hb2     = (const float*)d_in[24];
  float* out = (float*)d_out;

  float* ws  = (float*)d_ws;
  float* h   = ws;                         // NN*64 fp32
  float* xr  = h + (size_t)NN * 64;        // NN*64 fp32
  float* agg = xr + (size_t)NN * 64;       // NN*64 fp32
  float* fend = agg + (size_t)NN * 64;
  __hip_bfloat16* hb = (__hip_bfloat16*)fend;                   // NN*64
  __hip_bfloat16* qb = hb + (size_t)NN * 64;                    // NN*256
  __hip_bfloat16* kb = qb + (size_t)NN * 256;                   // NN*256
  __hip_bfloat16* vb = kb + (size_t)NN * 256;                   // NN*256
  __hip_bfloat16* Wb = vb + (size_t)NN * 256;                   // 2*53248
  int* cnt        = (int*)(Wb + 2 * 53248);                     // NN
  int* offs       = cnt + NN;                                   // NN+1
  int* cursor     = offs + NN + 1;                              // NN
  int* bsum       = cursor + NN;                                // NBLK
  int* bpre       = bsum + NBLK;                                // NBLK
  int* src_sorted = bpre + NBLK;                                // EE
  float4* ea_sorted = (float4*)(src_sorted + EE + 3);           // EE (16B align)

  // ---- CSR build (layer-independent, once per launch) ----
  hipMemsetAsync(cnt, 0, (size_t)NN * sizeof(int), stream);
  hist_kernel<<<977, 256, 0, stream>>>(ei, cnt);
  bsum_kernel<<<NBLK, 256, 0, stream>>>(cnt, bsum);
  bscan_kernel<<<1, 256, 0, stream>>>(bsum, bpre);
  scan2_kernel<<<NBLK, 256, 0, stream>>>(cnt, bpre, offs, cursor);
  scatter_kernel<<<977, 256, 0, stream>>>(ei, ea, cursor, src_sorted, ea_sorted);

  convert_wb_kernel<<<416, 256, 0, stream>>>(Wq, Wk, Wv, Wskip, Wb);
  enc_kernel<<<12500, 256, 0, stream>>>(x, enc_w1, enc_b1, enc_lng, enc_lnb,
                                        enc_w2, enc_b2, h, hb);

  for (int l = 0; l < 2; l++) {
    proj_mfma_kernel<<<782, 256, 0, stream>>>(
        hb, Wb + (size_t)l * 53248,
        bq + (size_t)l * 256, bk + (size_t)l * 256, bv + (size_t)l * 256,
        bskip + (size_t)l * 64, qb, kb, vb, xr);
    edge_fused_kernel<<<12500, 256, 0, stream>>>(
        offs, src_sorted, ea_sorted, qb, kb, vb, We + (size_t)l * 1024, agg);
    node_kernel<<<12500, 256, 0, stream>>>(agg, xr, h, hb, Wbeta + (size_t)l * 192,
                                           ln_g + (size_t)l * 64,
                                           ln_b + (size_t)l * 64);
  }

  head_kernel<<<6250, 256, 0, stream>>>(h, hw1, hb1, hw2, hb2, out);
}

// Round 12
// 389.899 us; speedup vs baseline: 1.3762x; 1.0619x over previous
//
#include <hip/hip_runtime.h>
#include <hip/hip_bf16.h>
#include <math.h>

#define NN 50000
#define EE 250000
#define SBLK 256
#define NBLK ((NN + SBLK - 1) / SBLK)   // 196

typedef __attribute__((ext_vector_type(8))) short bf16x8;
typedef __attribute__((ext_vector_type(4))) float f32x4;

__device__ __forceinline__ float wsum64(float v) {
  v += __shfl_xor(v, 1, 64);
  v += __shfl_xor(v, 2, 64);
  v += __shfl_xor(v, 4, 64);
  v += __shfl_xor(v, 8, 64);
  v += __shfl_xor(v, 16, 64);
  v += __shfl_xor(v, 32, 64);
  return v;
}

__device__ __forceinline__ int wsum64i(int v) {
  v += __shfl_xor(v, 1, 64);
  v += __shfl_xor(v, 2, 64);
  v += __shfl_xor(v, 4, 64);
  v += __shfl_xor(v, 8, 64);
  v += __shfl_xor(v, 16, 64);
  v += __shfl_xor(v, 32, 64);
  return v;
}

// inclusive wave scan (64 lanes)
__device__ __forceinline__ int wscan_inc(int v, int lane) {
  #pragma unroll
  for (int d = 1; d < 64; d <<= 1) {
    int u = __shfl_up(v, d, 64);
    if (lane >= d) v += u;
  }
  return v;
}

__device__ __forceinline__ float gelu_exact(float a) {
  return 0.5f * a * (1.0f + erff(a * 0.70710678118654752f));
}

__device__ __forceinline__ ushort f2bf(float f) {
  __hip_bfloat16 h = __float2bfloat16(f);
  return *reinterpret_cast<ushort*>(&h);
}

// convert 4 packed bf16 (8B as uint2) to 4 floats
__device__ __forceinline__ void bf4_to_f(const uint2 u, float* f) {
  f[0] = __uint_as_float(u.x << 16);
  f[1] = __uint_as_float(u.x & 0xffff0000u);
  f[2] = __uint_as_float(u.y << 16);
  f[3] = __uint_as_float(u.y & 0xffff0000u);
}

// ---------------- weight converter: Wq/Wk/Wv/Wskip -> bf16 MFMA-fragment layout
__global__ __launch_bounds__(256) void convert_wb_kernel(
    const float* __restrict__ Wq, const float* __restrict__ Wk,
    const float* __restrict__ Wv, const float* __restrict__ Ws,
    __hip_bfloat16* __restrict__ Wb) {
  const int tid = blockIdx.x * 256 + threadIdx.x;  // 0 .. 2*53248-1
  const int layer = tid / 53248;
  const int rem = tid % 53248;
  const int i = rem & 7;
  const int l = (rem >> 3) & 63;
  const int fct = rem >> 9;        // ct*2 + f
  const int f = fct & 1;
  const int ct = fct >> 1;
  const int col = ct * 16 + (l & 15);
  const int kk = f * 32 + (l >> 4) * 8 + i;
  float val;
  if (col < 256)      val = Wq[(size_t)layer * 16384 + kk * 256 + col];
  else if (col < 512) val = Wk[(size_t)layer * 16384 + kk * 256 + (col - 256)];
  else if (col < 768) val = Wv[(size_t)layer * 16384 + kk * 256 + (col - 512)];
  else                val = Ws[(size_t)layer * 4096 + kk * 64 + (col - 768)];
  Wb[tid] = __float2bfloat16(val);
}

// ---------------- CSR build ----------------
__global__ __launch_bounds__(256) void hist_kernel(const int* __restrict__ ei,
                                                   int* __restrict__ cnt) {
  const int e = blockIdx.x * 256 + threadIdx.x;
  if (e < EE) atomicAdd(&cnt[ei[EE + e]], 1);
}

__global__ __launch_bounds__(256) void bsum_kernel(const int* __restrict__ cnt,
                                                   int* __restrict__ bsum) {
  const int i = blockIdx.x * 256 + threadIdx.x;
  int v = (i < NN) ? cnt[i] : 0;
  v = wsum64i(v);
  __shared__ int ws_[4];
  if ((threadIdx.x & 63) == 0) ws_[threadIdx.x >> 6] = v;
  __syncthreads();
  if (threadIdx.x == 0) bsum[blockIdx.x] = ws_[0] + ws_[1] + ws_[2] + ws_[3];
}

__global__ __launch_bounds__(256) void bscan_kernel(const int* __restrict__ bsum,
                                                    int* __restrict__ bpre) {
  const int t = threadIdx.x;
  const int lane = t & 63;
  const int w = t >> 6;
  int orig = (t < NBLK) ? bsum[t] : 0;
  int v = wscan_inc(orig, lane);
  __shared__ int wtot[4];
  if (lane == 63) wtot[w] = v;
  __syncthreads();
  int add = 0;
  #pragma unroll
  for (int j = 0; j < 4; j++) if (j < w) add += wtot[j];
  if (t < NBLK) bpre[t] = v + add - orig;  // exclusive prefix
}

__global__ __launch_bounds__(256) void scan2_kernel(const int* __restrict__ cnt,
                                                    const int* __restrict__ bpre,
                                                    int* __restrict__ offs,
                                                    int* __restrict__ cursor) {
  const int i = blockIdx.x * 256 + threadIdx.x;
  const int t = threadIdx.x;
  const int lane = t & 63;
  const int w = t >> 6;
  int orig = (i < NN) ? cnt[i] : 0;
  int v = wscan_inc(orig, lane);
  __shared__ int wtot[4];
  if (lane == 63) wtot[w] = v;
  __syncthreads();
  int add = bpre[blockIdx.x];
  #pragma unroll
  for (int j = 0; j < 4; j++) if (j < w) add += wtot[j];
  int ex = v + add - orig;
  if (i < NN) { offs[i] = ex; cursor[i] = ex; }
  if (i == 0) offs[NN] = EE;
}

__global__ __launch_bounds__(256) void scatter_kernel(
    const int* __restrict__ ei, const float* __restrict__ ea,
    int* __restrict__ cursor, int* __restrict__ src_sorted,
    float4* __restrict__ ea_sorted) {
  const int e = blockIdx.x * 256 + threadIdx.x;
  if (e >= EE) return;
  const int dst = ei[EE + e];
  const int pos = atomicAdd(&cursor[dst], 1);
  src_sorted[pos] = ei[e];
  ea_sorted[pos] = reinterpret_cast<const float4*>(ea)[e];
}

// ---------------- encoder ----------------
__global__ __launch_bounds__(256) void enc_kernel(
    const float* __restrict__ x, const float* __restrict__ w1,
    const float* __restrict__ b1, const float* __restrict__ lg,
    const float* __restrict__ lb, const float* __restrict__ w2,
    const float* __restrict__ b2, float* __restrict__ h,
    __hip_bfloat16* __restrict__ hb) {
  const int t = blockIdx.x * 256 + threadIdx.x;
  const int node = t >> 6;
  const int lane = t & 63;
  const int wib = (threadIdx.x >> 6);
  __shared__ float gS[4][64];
  if (node < NN) {
    float a = b1[lane];
    #pragma unroll
    for (int d = 0; d < 6; d++) a += x[(size_t)node * 6 + d] * w1[d * 64 + lane];
    float g = gelu_exact(a);
    float s1 = wsum64(g);
    float s2 = wsum64(g * g);
    float m = s1 * (1.0f / 64.0f);
    float var = s2 * (1.0f / 64.0f) - m * m;
    g = (g - m) * rsqrtf(var + 1e-5f) * lg[lane] + lb[lane];
    gS[wib][lane] = g;
  }
  __syncthreads();
  if (node < NN) {
    float a = b2[lane];
    #pragma unroll 8
    for (int d = 0; d < 64; d++) a += gS[wib][d] * w2[d * 64 + lane];
    h[(size_t)node * 64 + lane] = a;
    hb[(size_t)node * 64 + lane] = __float2bfloat16(a);
  }
}

// ---------------- fused projections via MFMA (operand-swapped, ct-split, prefetched)
// grid = 1564: block b -> nodes (b>>1)*64.., ct half (b&1)*26..+26
// k/v interleaved: kv[node][cb*2 + 0..3] = k[cb..cb+3], kv[node][cb*2 + 4..7] = v[cb..cb+3]
// q pre-scaled by 0.125.
__global__ __launch_bounds__(256) void proj_mfma_kernel(
    const __hip_bfloat16* __restrict__ hbf,
    const __hip_bfloat16* __restrict__ Wb,
    const float* __restrict__ bq, const float* __restrict__ bk,
    const float* __restrict__ bv, const float* __restrict__ bs,
    __hip_bfloat16* __restrict__ q, __hip_bfloat16* __restrict__ kv,
    float* __restrict__ xr) {
  const int nb = blockIdx.x >> 1;
  const int half = blockIdx.x & 1;
  const int n0 = nb * 64;
  const int w = threadIdx.x >> 6;
  const int l = threadIdx.x & 63;
  const int r = l & 15;
  const int g = l >> 4;
  const int node = n0 + w * 16 + r;
  const int cg = g * 4;
  const bool in = (node < NN);

  bf16x8 A0 = {}, A1 = {};
  if (in) {
    const bf16x8* ap = reinterpret_cast<const bf16x8*>(hbf + (size_t)node * 64);
    A0 = ap[g];
    A1 = ap[g + 4];
  }

  const bf16x8* wb = reinterpret_cast<const bf16x8*>(Wb);
  const int ct0 = half * 26, ct1 = ct0 + 26;

  bf16x8 B0 = wb[(ct0 * 2 + 0) * 64 + l];
  bf16x8 B1 = wb[(ct0 * 2 + 1) * 64 + l];
  for (int ct = ct0; ct < ct1; ++ct) {
    bf16x8 C0 = B0, C1 = B1;
    if (ct + 1 < ct1) {                       // prefetch next B fragments
      B0 = wb[((ct + 1) * 2 + 0) * 64 + l];
      B1 = wb[((ct + 1) * 2 + 1) * 64 + l];
    }
    f32x4 acc = {0.f, 0.f, 0.f, 0.f};
    // SWAPPED: weights as A (=> W^T tile), h as B. D[wcol][node].
    acc = __builtin_amdgcn_mfma_f32_16x16x32_bf16(C0, A0, acc, 0, 0, 0);
    acc = __builtin_amdgcn_mfma_f32_16x16x32_bf16(C1, A1, acc, 0, 0, 0);
    if (!in) continue;
    if (ct < 16) {            // q
      const int cb = ct * 16 + cg;
      const float4 bb = *reinterpret_cast<const float4*>(bq + cb);
      uint2 pk;
      pk.x = (uint)f2bf((acc[0] + bb.x) * 0.125f) |
             ((uint)f2bf((acc[1] + bb.y) * 0.125f) << 16);
      pk.y = (uint)f2bf((acc[2] + bb.z) * 0.125f) |
             ((uint)f2bf((acc[3] + bb.w) * 0.125f) << 16);
      *reinterpret_cast<uint2*>(q + (size_t)node * 256 + cb) = pk;
    } else if (ct < 32) {     // k -> kv slot 0
      const int cb = (ct - 16) * 16 + cg;
      const float4 bb = *reinterpret_cast<const float4*>(bk + cb);
      uint2 pk;
      pk.x = (uint)f2bf(acc[0] + bb.x) | ((uint)f2bf(acc[1] + bb.y) << 16);
      pk.y = (uint)f2bf(acc[2] + bb.z) | ((uint)f2bf(acc[3] + bb.w) << 16);
      *reinterpret_cast<uint2*>(kv + (size_t)node * 512 + cb * 2) = pk;
    } else if (ct < 48) {     // v -> kv slot 1
      const int cb = (ct - 32) * 16 + cg;
      const float4 bb = *reinterpret_cast<const float4*>(bv + cb);
      uint2 pk;
      pk.x = (uint)f2bf(acc[0] + bb.x) | ((uint)f2bf(acc[1] + bb.y) << 16);
      pk.y = (uint)f2bf(acc[2] + bb.z) | ((uint)f2bf(acc[3] + bb.w) << 16);
      *reinterpret_cast<uint2*>(kv + (size_t)node * 512 + cb * 2 + 4) = pk;
    } else {                  // xr
      const int cb = (ct - 48) * 16 + cg;
      const float4 bb = *reinterpret_cast<const float4*>(bs + cb);
      float4 o = {acc[0] + bb.x, acc[1] + bb.y, acc[2] + bb.z, acc[3] + bb.w};
      *reinterpret_cast<float4*>(xr + (size_t)node * 64 + cb) = o;
    }
  }
}

// ---------------- fused edge + node update: one wave per dst node over CSR ----
// attention aggregate (head-mean) -> beta-gate -> residual -> LN, all in-wave.
__global__ __launch_bounds__(256) void edge_node_kernel(
    const int* __restrict__ offs, const int* __restrict__ src_sorted,
    const float4* __restrict__ ea_sorted,
    const __hip_bfloat16* __restrict__ qb, const __hip_bfloat16* __restrict__ kvb,
    const float* __restrict__ We, const float* __restrict__ xr,
    float* __restrict__ h, __hip_bfloat16* __restrict__ hb,
    const float* __restrict__ Wbt, const float* __restrict__ lg,
    const float* __restrict__ lb) {
  const int node = (blockIdx.x * 256 + threadIdx.x) >> 6;
  const int lane = threadIdx.x & 63;
  if (node >= NN) return;
  const int c0 = lane * 4;
  const ushort* q = reinterpret_cast<const ushort*>(qb);

  const float4 w0 = *reinterpret_cast<const float4*>(We + 0 * 256 + c0);
  const float4 w1 = *reinterpret_cast<const float4*>(We + 1 * 256 + c0);
  const float4 w2 = *reinterpret_cast<const float4*>(We + 2 * 256 + c0);
  const float4 w3 = *reinterpret_cast<const float4*>(We + 3 * 256 + c0);

  const int beg = offs[node];
  const int end = offs[node + 1];
  float qf[4];
  {
    uint2 qu = *reinterpret_cast<const uint2*>(q + (size_t)node * 256 + c0);
    bf4_to_f(qu, qf);
  }
  float m0 = 0.f, m1 = 0.f, m2 = 0.f, m3 = 0.f, sacc = 0.f;
  for (int e = beg; e < end; ++e) {
    const int src = src_sorted[e];
    const float4 av = ea_sorted[e];
    const float eh0 = av.x * w0.x + av.y * w1.x + av.z * w2.x + av.w * w3.x;
    const float eh1 = av.x * w0.y + av.y * w1.y + av.z * w2.y + av.w * w3.y;
    const float eh2 = av.x * w0.z + av.y * w1.z + av.z * w2.z + av.w * w3.z;
    const float eh3 = av.x * w0.w + av.y * w1.w + av.z * w2.w + av.w * w3.w;
    // one 16B gather: k (x,y) and v (z,w) interleaved per channel-group
    const uint4 kv = *reinterpret_cast<const uint4*>(
        kvb + (size_t)src * 512 + c0 * 2);
    float kf[4], vf[4];
    bf4_to_f(make_uint2(kv.x, kv.y), kf);
    bf4_to_f(make_uint2(kv.z, kv.w), vf);
    float d = qf[0] * (kf[0] + eh0) + qf[1] * (kf[1] + eh1) +
              qf[2] * (kf[2] + eh2) + qf[3] * (kf[3] + eh3);
    d += __shfl_xor(d, 1, 64);
    d += __shfl_xor(d, 2, 64);
    d += __shfl_xor(d, 4, 64);
    d += __shfl_xor(d, 8, 64);
    const float ex = __expf(d);  // softmax shift-invariance: no max pass needed
    sacc += ex;
    m0 += ex * (vf[0] + eh0);
    m1 += ex * (vf[1] + eh1);
    m2 += ex * (vf[2] + eh2);
    m3 += ex * (vf[3] + eh3);
  }
  const float inv = 0.25f / (sacc + 1e-16f);
  m0 *= inv; m1 *= inv; m2 *= inv; m3 *= inv;
  // mean over heads: lanes {l, l+16, l+32, l+48} share channel (l&15)*4+j
  m0 += __shfl_xor(m0, 16, 64); m0 += __shfl_xor(m0, 32, 64);
  m1 += __shfl_xor(m1, 16, 64); m1 += __shfl_xor(m1, 32, 64);
  m2 += __shfl_xor(m2, 16, 64); m2 += __shfl_xor(m2, 32, 64);
  m3 += __shfl_xor(m3, 16, 64); m3 += __shfl_xor(m3, 32, 64);

  // ---- fused node update (beta-gate + residual + LN), 4 channels/lane ----
  const int cb = (lane & 15) * 4;
  const float4 x4 = *reinterpret_cast<const float4*>(xr + (size_t)node * 64 + cb);
  const float4 h4 = *reinterpret_cast<const float4*>(h + (size_t)node * 64 + cb);
  float p = m0 * Wbt[cb + 0] + x4.x * Wbt[64 + cb + 0] + (m0 - x4.x) * Wbt[128 + cb + 0]
          + m1 * Wbt[cb + 1] + x4.y * Wbt[64 + cb + 1] + (m1 - x4.y) * Wbt[128 + cb + 1]
          + m2 * Wbt[cb + 2] + x4.z * Wbt[64 + cb + 2] + (m2 - x4.z) * Wbt[128 + cb + 2]
          + m3 * Wbt[cb + 3] + x4.w * Wbt[64 + cb + 3] + (m3 - x4.w) * Wbt[128 + cb + 3];
  p += __shfl_xor(p, 1, 64);
  p += __shfl_xor(p, 2, 64);
  p += __shfl_xor(p, 4, 64);
  p += __shfl_xor(p, 8, 64);
  const float beta = 1.0f / (1.0f + __expf(-p));
  float v0 = h4.x + beta * x4.x + (1.0f - beta) * m0;
  float v1 = h4.y + beta * x4.y + (1.0f - beta) * m1;
  float v2 = h4.z + beta * x4.z + (1.0f - beta) * m2;
  float v3 = h4.w + beta * x4.w + (1.0f - beta) * m3;
  float s1 = v0 + v1 + v2 + v3;
  float s2 = v0 * v0 + v1 * v1 + v2 * v2 + v3 * v3;
  s1 += __shfl_xor(s1, 1, 64); s2 += __shfl_xor(s2, 1, 64);
  s1 += __shfl_xor(s1, 2, 64); s2 += __shfl_xor(s2, 2, 64);
  s1 += __shfl_xor(s1, 4, 64); s2 += __shfl_xor(s2, 4, 64);
  s1 += __shfl_xor(s1, 8, 64); s2 += __shfl_xor(s2, 8, 64);
  const float mean = s1 * (1.0f / 64.0f);
  const float var = s2 * (1.0f / 64.0f) - mean * mean;
  const float rstd = rsqrtf(var + 1e-5f);
  const float4 g4 = *reinterpret_cast<const float4*>(lg + cb);
  const float4 b4 = *reinterpret_cast<const float4*>(lb + cb);
  const float r0 = (v0 - mean) * rstd * g4.x + b4.x;
  const float r1 = (v1 - mean) * rstd * g4.y + b4.y;
  const float r2 = (v2 - mean) * rstd * g4.z + b4.z;
  const float r3 = (v3 - mean) * rstd * g4.w + b4.w;
  if (lane < 16) {
    float4 o = {r0, r1, r2, r3};
    *reinterpret_cast<float4*>(h + (size_t)node * 64 + cb) = o;
    uint2 pk;
    pk.x = (uint)f2bf(r0) | ((uint)f2bf(r1) << 16);
    pk.y = (uint)f2bf(r2) | ((uint)f2bf(r3) << 16);
    *reinterpret_cast<uint2*>(hb + (size_t)node * 64 + cb) = pk;
  }
}

// ---------------- head ----------------
__global__ __launch_bounds__(256) void head_kernel(
    const float* __restrict__ h, const float* __restrict__ w1,
    const float* __restrict__ b1, const float* __restrict__ w2,
    const float* __restrict__ b2, float* __restrict__ out) {
  const int base_node = blockIdx.x * 8;
  const int nib = threadIdx.x >> 5;
  const int c = threadIdx.x & 31;
  __shared__ float hS[8][64];
  #pragma unroll
  for (int i = 0; i < 2; i++) {
    int idx = threadIdx.x + i * 256;
    int nn = idx >> 6, d = idx & 63;
    if (base_node + nn < NN) hS[nn][d] = h[(size_t)(base_node + nn) * 64 + d];
  }
  __syncthreads();
  const int node = base_node + nib;
  if (node < NN) {
    float a = b1[c];
    #pragma unroll 8
    for (int d = 0; d < 64; d++) a += hS[nib][d] * w1[d * 32 + c];
    float g = gelu_exact(a);
    float p0 = g * w2[c * 2 + 0];
    float p1 = g * w2[c * 2 + 1];
    #pragma unroll
    for (int m = 1; m < 32; m <<= 1) {
      p0 += __shfl_xor(p0, m, 64);
      p1 += __shfl_xor(p1, m, 64);
    }
    if (c == 0) {
      out[(size_t)node * 2 + 0] = p0 + b2[0];
      out[(size_t)node * 2 + 1] = p1 + b2[1];
    }
  }
}

extern "C" void kernel_launch(void* const* d_in, const int* in_sizes, int n_in,
                              void* d_out, int out_size, void* d_ws, size_t ws_size,
                              hipStream_t stream) {
  const float* x       = (const float*)d_in[0];
  const int*   ei      = (const int*)d_in[1];
  const float* ea      = (const float*)d_in[2];
  const float* enc_w1  = (const float*)d_in[3];
  const float* enc_b1  = (const float*)d_in[4];
  const float* enc_lng = (const float*)d_in[5];
  const float* enc_lnb = (const float*)d_in[6];
  const float* enc_w2  = (const float*)d_in[7];
  const float* enc_b2  = (const float*)d_in[8];
  const float* Wq      = (const float*)d_in[9];
  const float* bq      = (const float*)d_in[10];
  const float* Wk      = (const float*)d_in[11];
  const float* bk      = (const float*)d_in[12];
  const float* Wv      = (const float*)d_in[13];
  const float* bv      = (const float*)d_in[14];
  const float* We      = (const float*)d_in[15];
  const float* Wskip   = (const float*)d_in[16];
  const float* bskip   = (const float*)d_in[17];
  const float* Wbeta   = (const float*)d_in[18];
  const float* ln_g    = (const float*)d_in[19];
  const float* ln_b    = (const float*)d_in[20];
  const float* hw1     = (const float*)d_in[21];
  const float* hb1     = (const float*)d_in[22];
  const float* hw2     = (const float*)d_in[23];
  const float* hb2     = (const float*)d_in[24];
  float* out = (float*)d_out;

  float* ws  = (float*)d_ws;
  float* h   = ws;                         // NN*64 fp32
  float* xr  = h + (size_t)NN * 64;        // NN*64 fp32
  float* fend = xr + (size_t)NN * 64;
  __hip_bfloat16* hb = (__hip_bfloat16*)fend;                   // NN*64
  __hip_bfloat16* qb = hb + (size_t)NN * 64;                    // NN*256
  __hip_bfloat16* kvb = qb + (size_t)NN * 256;                  // NN*512 (k|v interleaved)
  __hip_bfloat16* Wb = kvb + (size_t)NN * 512;                  // 2*53248
  int* cnt        = (int*)(Wb + 2 * 53248);                     // NN
  int* offs       = cnt + NN;                                   // NN+1
  int* cursor     = offs + NN + 1;                              // NN
  int* bsum       = cursor + NN;                                // NBLK
  int* bpre       = bsum + NBLK;                                // NBLK
  int* src_sorted = bpre + NBLK;                                // EE
  float4* ea_sorted = (float4*)(src_sorted + EE + 3);           // EE (16B align)

  // ---- CSR build (layer-independent, once per launch) ----
  hipMemsetAsync(cnt, 0, (size_t)NN * sizeof(int), stream);
  hist_kernel<<<977, 256, 0, stream>>>(ei, cnt);
  bsum_kernel<<<NBLK, 256, 0, stream>>>(cnt, bsum);
  bscan_kernel<<<1, 256, 0, stream>>>(bsum, bpre);
  scan2_kernel<<<NBLK, 256, 0, stream>>>(cnt, bpre, offs, cursor);
  scatter_kernel<<<977, 256, 0, stream>>>(ei, ea, cursor, src_sorted, ea_sorted);

  convert_wb_kernel<<<416, 256, 0, stream>>>(Wq, Wk, Wv, Wskip, Wb);
  enc_kernel<<<12500, 256, 0, stream>>>(x, enc_w1, enc_b1, enc_lng, enc_lnb,
                                        enc_w2, enc_b2, h, hb);

  for (int l = 0; l < 2; l++) {
    proj_mfma_kernel<<<1564, 256, 0, stream>>>(
        hb, Wb + (size_t)l * 53248,
        bq + (size_t)l * 256, bk + (size_t)l * 256, bv + (size_t)l * 256,
        bskip + (size_t)l * 64, qb, kvb, xr);
    edge_node_kernel<<<12500, 256, 0, stream>>>(
        offs, src_sorted, ea_sorted, qb, kvb, We + (size_t)l * 1024, xr,
        h, hb, Wbeta + (size_t)l * 192, ln_g + (size_t)l * 64,
        ln_b + (size_t)l * 64);
  }

  head_kernel<<<6250, 256, 0, stream>>>(h, hw1, hb1, hw2, hb2, out);
}